// Round 1
// baseline (182.752 us; speedup 1.0000x reference)
//
#include <hip/hip_runtime.h>
#include <math.h>

#define C_CAND 10

__global__ __launch_bounds__(256) void wootGlobalToLocal_kernel(
    const float* __restrict__ query_xyz,
    const float* __restrict__ temp_verts,
    const int*   __restrict__ faces,
    const int*   __restrict__ cand_ids,
    float*       __restrict__ out_ret,   // face id as float
    float*       __restrict__ out_md,
    int n)
{
#pragma clang fp contract(off)
    int i = blockIdx.x * blockDim.x + threadIdx.x;
    if (i >= n) return;

    const float qx = query_xyz[3*i + 0];
    const float qy = query_xyz[3*i + 1];
    const float qz = query_xyz[3*i + 2];

    float best_abs = 0.0f;
    float best_md  = 0.0f;
    int   best_f   = 0;

    for (int j = 0; j < C_CAND; ++j) {
        const int f  = cand_ids[i * C_CAND + j];
        const int i0 = faces[3*f + 0];
        const int i1 = faces[3*f + 1];
        const int i2 = faces[3*f + 2];

        const float v0x = temp_verts[3*i0 + 0];
        const float v0y = temp_verts[3*i0 + 1];
        const float v0z = temp_verts[3*i0 + 2];
        const float v1x = temp_verts[3*i1 + 0];
        const float v1y = temp_verts[3*i1 + 1];
        const float v1z = temp_verts[3*i1 + 2];
        const float v2x = temp_verts[3*i2 + 0];
        const float v2y = temp_verts[3*i2 + 1];
        const float v2z = temp_verts[3*i2 + 2];

        // edges
        const float e10x = v1x - v0x, e10y = v1y - v0y, e10z = v1z - v0z;
        const float e21x = v2x - v1x, e21y = v2y - v1y, e21z = v2z - v1z;
        const float e02x = v0x - v2x, e02y = v0y - v2y, e02z = v0z - v2z;

        // fN = -cross(e10, e02)  (cross computed first, then negated — numpy order)
        const float crx = e10y*e02z - e10z*e02y;
        const float cry = e10z*e02x - e10x*e02z;
        const float crz = e10x*e02y - e10y*e02x;
        const float fNx = -crx, fNy = -cry, fNz = -crz;

        // q - v0/v1/v2
        const float a0x = qx - v0x, a0y = qy - v0y, a0z = qz - v0z;
        const float a1x = qx - v1x, a1y = qy - v1y, a1z = qz - v1z;
        const float a2x = qx - v2x, a2y = qy - v2y, a2z = qz - v2z;

        // edge projections: dot(p - v, e) / max(dot(e,e), eps)
        const float num_ab = (a0x*e10x + a0y*e10y) + a0z*e10z;
        const float den_ab = fmaxf((e10x*e10x + e10y*e10y) + e10z*e10z, 1e-9f);
        const float uab = num_ab / den_ab;

        const float num_bc = (a1x*e21x + a1y*e21y) + a1z*e21z;
        const float den_bc = fmaxf((e21x*e21x + e21y*e21y) + e21z*e21z, 1e-9f);
        const float ubc = num_bc / den_bc;

        const float num_ca = (a2x*e02x + a2y*e02y) + a2z*e02z;
        const float den_ca = fmaxf((e02x*e02x + e02y*e02y) + e02z*e02z, 1e-9f);
        const float uca = num_ca / den_ca;

        // region flags
        const bool t1 = (uca > 1.0f) && (uab < 0.0f);
        const bool t2 = (uab > 1.0f) && (ubc < 0.0f);
        const bool t3 = (ubc > 1.0f) && (uca < 0.0f);

        // _is_not_above(v, e, n, p): dot(cross(n, e), p - v) <= 0
        // cross(fN, e10)
        const float c0x = fNy*e10z - fNz*e10y;
        const float c0y = fNz*e10x - fNx*e10z;
        const float c0z = fNx*e10y - fNy*e10x;
        const bool na0 = ((c0x*a0x + c0y*a0y) + c0z*a0z) <= 0.0f;
        // cross(fN, e21)
        const float c1x = fNy*e21z - fNz*e21y;
        const float c1y = fNz*e21x - fNx*e21z;
        const float c1z = fNx*e21y - fNy*e21x;
        const bool na1 = ((c1x*a1x + c1y*a1y) + c1z*a1z) <= 0.0f;
        // cross(fN, e02)
        const float c2x = fNy*e02z - fNz*e02y;
        const float c2y = fNz*e02x - fNx*e02z;
        const float c2z = fNx*e02y - fNy*e02x;
        const bool na2 = ((c2x*a2x + c2y*a2y) + c2z*a2z) <= 0.0f;

        const bool t4 = (uab >= 0.0f) && (uab <= 1.0f) && na0;
        const bool t5 = (ubc >= 0.0f) && (ubc <= 1.0f) && na1 && !t4;
        const bool t6 = (uca >= 0.0f) && (uca <= 1.0f) && na2 && !t4 && !t5;
        const bool t0 = !(t1 || t2 || t3 || t4 || t5 || t6);

        // unit normal: fN / max(||fN||, eps)  — three scalar divides, numpy order
        const float nrm = sqrtf((fNx*fNx + fNy*fNy) + fNz*fNz);
        const float dnm = fmaxf(nrm, 1e-9f);
        const float unx = fNx / dnm;
        const float uny = fNy / dnm;
        const float unz = fNz / dnm;

        const float d0 = (a0x*unx + a0y*uny) + a0z*unz;
        const float d1 = sqrtf((a0x*a0x + a0y*a0y) + a0z*a0z);
        const float d2 = sqrtf((a1x*a1x + a1y*a1y) + a1z*a1z);
        const float d3 = sqrtf((a2x*a2x + a2y*a2y) + a2z*a2z);

        // closest points on edges
        const float p4x = v0x + e10x*uab, p4y = v0y + e10y*uab, p4z = v0z + e10z*uab;
        const float p5x = v1x + e21x*ubc, p5y = v1y + e21y*ubc, p5z = v1z + e21z*ubc;
        const float p6x = v2x + e02x*uca, p6y = v2y + e02y*uca, p6z = v2z + e02z*uca;

        const float g4x = qx - p4x, g4y = qy - p4y, g4z = qz - p4z;
        const float g5x = qx - p5x, g5y = qy - p5y, g5z = qz - p5z;
        const float g6x = qx - p6x, g6y = qy - p6y, g6z = qz - p6z;

        const float d4 = sqrtf((g4x*g4x + g4y*g4y) + g4z*g4z);
        const float d5 = sqrtf((g5x*g5x + g5y*g5y) + g5z*g5z);
        const float d6 = sqrtf((g6x*g6x + g6y*g6y) + g6z*g6z);

        // merged = d0*t0 + d1*t1 + ... + d6*t6, left-associated like the reference
        float merged = d0 * (t0 ? 1.0f : 0.0f);
        merged = merged + d1 * (t1 ? 1.0f : 0.0f);
        merged = merged + d2 * (t2 ? 1.0f : 0.0f);
        merged = merged + d3 * (t3 ? 1.0f : 0.0f);
        merged = merged + d4 * (t4 ? 1.0f : 0.0f);
        merged = merged + d5 * (t5 ? 1.0f : 0.0f);
        merged = merged + d6 * (t6 ? 1.0f : 0.0f);

        const float am = fabsf(merged);
        // strict < keeps the FIRST minimum, matching np.argmin tie-break
        if (j == 0 || am < best_abs) {
            best_abs = am;
            best_md  = merged;
            best_f   = f;
        }
    }

    out_ret[i] = (float)best_f;
    out_md[i]  = best_md;
}

extern "C" void kernel_launch(void* const* d_in, const int* in_sizes, int n_in,
                              void* d_out, int out_size, void* d_ws, size_t ws_size,
                              hipStream_t stream) {
    const float* query_xyz  = (const float*)d_in[0];
    const float* temp_verts = (const float*)d_in[1];
    const int*   faces      = (const int*)d_in[2];
    const int*   cand_ids   = (const int*)d_in[3];

    const int n = in_sizes[0] / 3;   // N queries

    float* out_ret = (float*)d_out;      // first N elements: chosen face id (as float)
    float* out_md  = out_ret + n;        // next N elements: merged distance

    const int block = 256;
    const int grid  = (n + block - 1) / block;
    wootGlobalToLocal_kernel<<<grid, block, 0, stream>>>(
        query_xyz, temp_verts, faces, cand_ids, out_ret, out_md, n);
}